// Round 4
// baseline (200.797 us; speedup 1.0000x reference)
//
#include <hip/hip_runtime.h>
#include <stdint.h>

#define NPIX 65536
#define IGN (-255)
#define CAP 768          // global candidate list capacity per region (mu+32sigma)
#define LCAP 192         // per-block LDS candidate capacity per region (mu+28sigma)
// per-image scratch layout inside out[b*NPIX + ...] (ints 0..20479 = rows 0..79)
//   ints 0..16383      packed u8 image (4 px/int, little-endian)
#define HPART  16384     // 8 x 256 per-block hist partials
#define M_CF   18432     // fg candidate count
#define M_CB   18433     // bg candidate count
#define M_THR  18434     // qthr: fg iff q >= qthr
#define M_NROI 18435     // exact roi size
#define M_FG   18436     // 768 fg candidate pixel indices
#define M_BG   19204     // 768 bg candidate pixel indices; ends 19972
#define SCR_I4 5120      // scratch size in int4 (ints 0..20479)

// ---------------- threefry2x32 (exact JAX partitionable implementation) ----------------
__device__ __forceinline__ uint32_t rotl32(uint32_t v, uint32_t r){ return (v<<r)|(v>>(32u-r)); }

__device__ __forceinline__ void tf2x32(uint32_t k0, uint32_t k1, uint32_t x0, uint32_t x1,
                                       uint32_t &o0, uint32_t &o1){
  uint32_t k2 = k0 ^ k1 ^ 0x1BD11BDAu;
  x0 += k0; x1 += k1;
#define TFR(r) { x0 += x1; x1 = rotl32(x1,(r)); x1 ^= x0; }
  TFR(13u) TFR(15u) TFR(26u) TFR(6u)   x0 += k1; x1 += k2 + 1u;
  TFR(17u) TFR(29u) TFR(16u) TFR(24u)  x0 += k2; x1 += k0 + 2u;
  TFR(13u) TFR(15u) TFR(26u) TFR(6u)   x0 += k0; x1 += k1 + 3u;
  TFR(17u) TFR(29u) TFR(16u) TFR(24u)  x0 += k1; x1 += k2 + 4u;
  TFR(13u) TFR(15u) TFR(26u) TFR(6u)   x0 += k2; x1 += k0 + 5u;
#undef TFR
  o0 = x0; o1 = x1;
}

// pack score+index so that u64 max == (higher score, then lower index)
__device__ __forceinline__ unsigned long long packCand(uint32_t bits, uint32_t pix){
  float f = __uint_as_float((bits >> 9) | 0x3f800000u) - 1.0f;  // jax uniform [0,1)
  uint32_t u = __float_as_uint(f) ^ 0x80000000u;                // monotone map (f>=0)
  return ((unsigned long long)u << 32) | (unsigned long long)(0xFFFFFFFFu - pix);
}

// sorted-descending 10-element list, sentinel 0
__device__ __forceinline__ void t10_insert(unsigned long long* l, unsigned long long c){
  if (c > l[9]) {
    l[9] = c;
#pragma unroll
    for (int i = 9; i > 0; --i){
      unsigned long long a = l[i-1], b2 = l[i];
      if (b2 > a){ l[i-1] = b2; l[i] = a; }
    }
  }
}

// ------- K1: quantize->u8 scratch, IGN fill (non-scratch), hist partials, zero counters ---
__global__ __launch_bounds__(256, 8)
void k1_hist_fill(const float* __restrict__ x, int* __restrict__ out){
  const int blk = blockIdx.x;
  const int b = blk >> 3, j8 = blk & 7;     // 8 blocks per image, 8192 px each
  const int tid = threadIdx.x;
  const float4* x4 = (const float4*)(x + (size_t)b * NPIX);
  int* base = out + (size_t)b * NPIX;
  int4* o4 = (int4*)base;

  __shared__ uint32_t histR[1024];          // 256 bins x 4 lane-columns (conflict spread)
#pragma unroll
  for (int k = 0; k < 4; ++k) histR[tid + 256*k] = 0u;
  if (j8 == 0 && tid == 0){ base[M_CF] = 0; base[M_CB] = 0; }
  __syncthreads();

  const int4 f4 = make_int4(IGN, IGN, IGN, IGN);
  const uint32_t c4 = (uint32_t)(tid & 3);
#pragma unroll
  for (int jj = 0; jj < 8; ++jj){
    int i4 = j8*2048 + jj*256 + tid;        // global float4 / packed-int / out-int4 index
    float4 v = x4[i4];
    uint32_t u0 = (uint32_t)min(max((int)floorf(v.x*255.0f),0),255);
    uint32_t u1 = (uint32_t)min(max((int)floorf(v.y*255.0f),0),255);
    uint32_t u2 = (uint32_t)min(max((int)floorf(v.z*255.0f),0),255);
    uint32_t u3 = (uint32_t)min(max((int)floorf(v.w*255.0f),0),255);
    base[i4] = (int)(u0 | (u1<<8) | (u2<<16) | (u3<<24));   // u8 scratch (ints 0..16383)
    if (i4 >= SCR_I4) o4[i4] = f4;          // IGN, skipping scratch ints 0..20479
    atomicAdd(&histR[(u0<<2)|c4],1u); atomicAdd(&histR[(u1<<2)|c4],1u);
    atomicAdd(&histR[(u2<<2)|c4],1u); atomicAdd(&histR[(u3<<2)|c4],1u);
  }
  __syncthreads();
  uint32_t s = histR[4*tid] + histR[4*tid+1] + histR[4*tid+2] + histR[4*tid+3];
  base[HPART + j8*256 + tid] = (int)s;      // plain store: no zeroing pass needed
}

// ------- K2: per-block threshold recompute (hist->scan->Otsu->Li), threefry scoring, ------
// -------     LDS candidate aggregation -> one global atomicAdd + bulk copy           ------
__global__ __launch_bounds__(256, 8)
void k2_score(int* __restrict__ out){
  const int blk = blockIdx.x;
  const int b = blk >> 3, j8 = blk & 7;
  const int tid = threadIdx.x;
  int* meta = out + (size_t)b * NPIX;

  __shared__ float csum[256], cvsum[256];
  __shared__ int s_imin, s_qthr;
  __shared__ unsigned long long s_best;
  __shared__ uint32_t s_kw[4];
  __shared__ int s_lcnt[2], s_base[2];
  __shared__ int s_lbuf[2][LCAP];

  if (tid == 0){ s_imin = 255; s_best = 0ull; s_lcnt[0] = 0; s_lcnt[1] = 0; }
  if (tid < 2){
    uint32_t o0, o1;
    tf2x32(0u, 1u, 0u, (uint32_t)(2*b + tid), o0, o1);
    s_kw[2*tid] = o0; s_kw[2*tid+1] = o1;
  }
  __syncthreads();

  // ---- threshold (redundant per block; deterministic identical result) ----
  int h = 0;
#pragma unroll
  for (int j = 0; j < 8; ++j) h += meta[HPART + j*256 + tid];
  if (h) atomicMin(&s_imin, tid);
  __syncthreads();
  const float img_min = (float)s_imin;

  csum[tid]  = (float)h;
  cvsum[tid] = (float)h * ((float)tid - img_min);
  __syncthreads();
  for (int off = 1; off < 256; off <<= 1){
    float a = 0.f, c2 = 0.f;
    if (tid >= off){ a = csum[tid-off]; c2 = cvsum[tid-off]; }
    __syncthreads();
    if (tid >= off){ csum[tid] += a; cvsum[tid] += c2; }
    __syncthreads();
  }
  {
    float s_tot_o = cvsum[255] + img_min * csum[255];
    if (tid < 255){
      float w0 = csum[tid];
      float w1 = 65536.0f - w0;
      float cs = cvsum[tid] + img_min * csum[tid];
      float m0 = cs / fmaxf(w0, 1e-12f);
      float m1 = (s_tot_o - cs) / fmaxf(w1, 1e-12f);
      float d = m0 - m1;
      float vb = (w0*w1) * (d*d);
      unsigned long long pk =
        ((unsigned long long)__float_as_uint(vb) << 32) | (unsigned long long)(255 - tid);
      atomicMax(&s_best, pk);
    }
  }
  __syncthreads();
  if (tid == 0){
    int bestIdx = 255 - (int)(s_best & 0xFFFFFFFFull);
    float otsu = fminf(fmaxf((float)bestIdx, 1.0f), 254.0f);
    float n_tot = csum[255], s_tot = cvsum[255];
    float t_curr = otsu - img_min, t_prev = t_curr + 10.0f;
    int it = 0;
    while (fabsf(t_curr - t_prev) > 0.5f && it < 64){
      int idx = min(max((int)floorf(t_curr + img_min), 0), 255);
      float n_back = csum[idx], s_back = cvsum[idx];
      float n_fore = n_tot - n_back, s_fore = s_tot - s_back;
      float mean_back = (n_back > 0.0f) ? (s_back / fmaxf(n_back, 1.0f)) : 0.0f;
      float mean_fore = s_fore / fmaxf(n_fore, 1.0f);
      float t_next = (mean_back - mean_fore) /
                     (logf(fmaxf(mean_back, 1e-12f)) - logf(fmaxf(mean_fore, 1e-12f)));
      if (mean_back < 1e-12f) t_next = mean_fore * 0.5f;
      t_prev = t_curr; t_curr = t_next; ++it;
    }
    float lit = t_curr + img_min;
    // integer threshold: for integer q, (float)q > lit  <=>  q >= floor(lit)+1
    // NaN lit (degenerate image): predicate false for all q -> qthr=256
    int qthr;
    if (!(lit == lit)) qthr = 256;
    else               qthr = (int)floorf(lit) + 1;
    s_qthr = qthr;
    if (j8 == 0){
      meta[M_THR] = qthr;
      int nlo = (qthr <= 0) ? 0 : (int)csum[min(qthr, 256) - 1];
      meta[M_NROI] = NPIX - nlo;       // exact nroi = count(q > lit)
    }
  }
  __syncthreads();

  // ---- scoring: threefry per pixel, LDS-aggregated candidate push ----
  const int qthr = s_qthr;
  const uint32_t fk0 = s_kw[0], fk1 = s_kw[1], bk0 = s_kw[2], bk1 = s_kw[3];
  const int4* u4 = (const int4*)meta;       // packed u8 image as int4 (16 px each)
  int4 w0 = u4[j8*512 + tid];
  int4 w1 = u4[j8*512 + 256 + tid];
  const uint32_t pixA = (uint32_t)(j8*8192 + 16*tid);
  const uint32_t pixB = pixA + 4096u;
#pragma unroll
  for (int half = 0; half < 2; ++half){
    int4 w = half ? w1 : w0;
    uint32_t pb = half ? pixB : pixA;
    const uint32_t words[4] = {(uint32_t)w.x,(uint32_t)w.y,(uint32_t)w.z,(uint32_t)w.w};
#pragma unroll
    for (int m = 0; m < 4; ++m){
      uint32_t pk = words[m];
#pragma unroll
      for (int s = 0; s < 4; ++s){
        int q = (int)((pk >> (8*s)) & 255u);
        bool r = (q >= qthr);
        uint32_t pix = pb + (uint32_t)(4*m + s);
        uint32_t o0, o1;
        tf2x32(r ? fk0 : bk0, r ? fk1 : bk1, 0u, pix, o0, o1);
        uint32_t bits = o0 ^ o1;
        if (bits >= 0xFF000000u){         // == (bits>>9) >= THRM, mantissa-aligned cut
          int r2 = r ? 0 : 1;
          int idx = atomicAdd(&s_lcnt[r2], 1);
          if (idx < LCAP) s_lbuf[r2][idx] = (int)pix;
        }
      }
    }
  }
  __syncthreads();
  if (tid < 2){
    int n = s_lcnt[tid];
    // local overflow (statistically never): inflate count past CAP -> forces fallback
    int add = (n > LCAP) ? (n + CAP + 1) : n;
    s_base[tid] = atomicAdd(&meta[M_CF + tid], add);   // exact global count
  }
  __syncthreads();
#pragma unroll
  for (int r2 = 0; r2 < 2; ++r2){
    int n = min(s_lcnt[r2], LCAP);
    int bse = s_base[r2];
    for (int i = tid; i < n; i += 256){
      int g = bse + i;
      if (g < CAP) meta[(r2 ? M_BG : M_FG) + g] = s_lbuf[r2][i];
    }
  }
}

// ------- K3: fail-check+fallback, parallel top-10 extract, scratch IGN-fill, patches ------
__global__ __launch_bounds__(256, 4)
void k3_final(int* __restrict__ out){
  const int b = blockIdx.x;
  const int tid = threadIdx.x;
  int* meta = out + (size_t)b * NPIX;
  int* outb = meta;

  __shared__ unsigned long long s_top[2][64][10];
  __shared__ unsigned long long s_top2[2][8][10];
  __shared__ uint32_t s_kw[4];
  __shared__ int s_cnt[2], s_fail[2], s_np[2];
  __shared__ int s_qthr;
  __shared__ int s_pr[2][10], s_pc[2][10];

  if (tid < 2){
    uint32_t o0, o1;
    tf2x32(0u, 1u, 0u, (uint32_t)(2*b + tid), o0, o1);
    s_kw[2*tid] = o0; s_kw[2*tid+1] = o1;
  }
  if (tid == 0){
    s_qthr = meta[M_THR];
    int nroi = meta[M_NROI];
    int c0 = meta[M_CF], c1 = meta[M_CB];
    s_cnt[0] = c0; s_cnt[1] = c1;
    s_fail[0] = (c0 > CAP) || (c0 < 10 && c0 != nroi);
    s_fail[1] = (c1 > CAP) || (c1 < 10 && c1 != NPIX - nroi);
  }
  __syncthreads();

  // ---- per-lane top-10 (wave 0 -> fg, wave 1 -> bg); fallback scans u8 image ----
  const int wv = tid >> 6, lane = tid & 63;
  if (wv < 2){
    const int r2 = wv;
    unsigned long long t[10];
#pragma unroll
    for (int i = 0; i < 10; ++i) t[i] = 0ull;
    const uint32_t kk0 = s_kw[2*r2], kk1 = s_kw[2*r2+1];
    if (!s_fail[r2]){
      int n = min(s_cnt[r2], CAP);
      for (int i = lane; i < n; i += 64){
        uint32_t pix = (uint32_t)meta[(r2 ? M_BG : M_FG) + i];
        uint32_t o0, o1; tf2x32(kk0, kk1, 0u, pix, o0, o1);
        t10_insert(t, packCand(o0 ^ o1, pix));
      }
    } else {
      const int qthr = s_qthr;
      for (int k = 0; k < 1024; ++k){
        uint32_t pix = (uint32_t)(lane + 64*k);
        int q = (int)(((uint32_t)meta[pix >> 2] >> (8*(pix & 3u))) & 255u);
        bool r = (q >= qthr);
        if (r == (r2 == 0)){
          uint32_t o0, o1; tf2x32(kk0, kk1, 0u, pix, o0, o1);
          t10_insert(t, packCand(o0 ^ o1, pix));
        }
      }
    }
#pragma unroll
    for (int i = 0; i < 10; ++i) s_top[r2][lane][i] = t[i];
  }
  __syncthreads();
  // ---- merge 64 -> 8 ----
  if (wv < 2 && lane < 8){
    unsigned long long t[10];
#pragma unroll
    for (int i = 0; i < 10; ++i) t[i] = 0ull;
    for (int l2 = 0; l2 < 8; ++l2)
#pragma unroll
      for (int i = 0; i < 10; ++i) t10_insert(t, s_top[wv][lane*8 + l2][i]);
#pragma unroll
    for (int i = 0; i < 10; ++i) s_top2[wv][lane][i] = t[i];
  }
  __syncthreads();
  // ---- merge 8 -> 1, extract points ----
  if (wv < 2 && lane == 0){
    unsigned long long t[10];
#pragma unroll
    for (int i = 0; i < 10; ++i) t[i] = 0ull;
    for (int l2 = 0; l2 < 8; ++l2)
#pragma unroll
      for (int i = 0; i < 10; ++i) t10_insert(t, s_top2[wv][l2][i]);
    int np = 0;
    for (int i = 0; i < 10; ++i){
      if (t[i]){
        uint32_t pix = 0xFFFFFFFFu - (uint32_t)(t[i] & 0xFFFFFFFFull);
        s_pr[wv][np] = (int)(pix >> 8);
        s_pc[wv][np] = (int)(pix & 255u);
        ++np;
      }
    }
    s_np[wv] = np;
  }
  __syncthreads();

  // ---- overwrite scratch ints 0..20479 with IGN (candidates already consumed) ----
  const int4 f4 = make_int4(IGN, IGN, IGN, IGN);
#pragma unroll
  for (int k = 0; k < 20; ++k)
    ((int4*)meta)[tid + 256*k] = f4;
  __syncthreads();

  // ---- write dilated seed patches (<=180 px); duplicates write identical values ----
  const int nfg = s_np[0], nbg = s_np[1];
  const int npts = nfg + nbg;
  if (tid < npts*9){
    int k = tid / 9, d = tid - k*9;
    int pr = (k < nfg) ? s_pr[0][k] : s_pr[1][k - nfg];
    int pc = (k < nfg) ? s_pc[0][k] : s_pc[1][k - nfg];
    pr += d/3 - 1; pc += d%3 - 1;
    if (pr >= 0 && pr < 256 && pc >= 0 && pc < 256){
      bool fgd = false, bgd = false;
      for (int i = 0; i < nfg; ++i) fgd |= (abs(pr - s_pr[0][i]) <= 1) && (abs(pc - s_pc[0][i]) <= 1);
      for (int i = 0; i < nbg; ++i) bgd |= (abs(pr - s_pr[1][i]) <= 1) && (abs(pc - s_pc[1][i]) <= 1);
      int val = (fgd && bgd) ? IGN : (fgd ? 1 : 0);
      outb[pr*256 + pc] = val;
    }
  }
}

extern "C" void kernel_launch(void* const* d_in, const int* in_sizes, int n_in,
                              void* d_out, int out_size, void* d_ws, size_t ws_size,
                              hipStream_t stream) {
  const float* x = (const float*)d_in[0];
  int* out = (int*)d_out;
  int B = in_sizes[0] / NPIX;
  k1_hist_fill<<<8*B, 256, 0, stream>>>(x, out);
  k2_score    <<<8*B, 256, 0, stream>>>(out);
  k3_final    <<<B,   256, 0, stream>>>(out);
}

// Round 5
// 191.591 us; speedup vs baseline: 1.0480x; 1.0480x over previous
//
#include <hip/hip_runtime.h>
#include <stdint.h>

#define NPIX 65536
#define IGN (-255)
#define SEGC 96          // per-block per-region segment capacity (mean 32, +11sigma)
#define GCAP 768         // 8 segments x 96
// per-image scratch layout inside out[b*NPIX + ...] (ints 0..4095 = rows 0..15)
#define FGSEG 0          // 768: fg-key hit pixel indices (8 segs x 96)
#define BGSEG 768        // 768: bg-key hit pixel indices
#define CNTF  1536       // 8: per-block fg hit counts (raw, may exceed SEGC)
#define CNTB  1544       // 8: per-block bg hit counts
#define HPART 1552       // 2048: 8 x 256 hist partials; ends 3600 < 4096
#define SCRI4 1024       // scratch size in int4 (ints 0..4095)

// ---------------- threefry2x32 (exact JAX partitionable implementation) ----------------
__device__ __forceinline__ uint32_t rotl32(uint32_t v, uint32_t r){ return (v<<r)|(v>>(32u-r)); }

__device__ __forceinline__ void tf2x32(uint32_t k0, uint32_t k1, uint32_t x0, uint32_t x1,
                                       uint32_t &o0, uint32_t &o1){
  uint32_t k2 = k0 ^ k1 ^ 0x1BD11BDAu;
  x0 += k0; x1 += k1;
#define TFR(r) { x0 += x1; x1 = rotl32(x1,(r)); x1 ^= x0; }
  TFR(13u) TFR(15u) TFR(26u) TFR(6u)   x0 += k1; x1 += k2 + 1u;
  TFR(17u) TFR(29u) TFR(16u) TFR(24u)  x0 += k2; x1 += k0 + 2u;
  TFR(13u) TFR(15u) TFR(26u) TFR(6u)   x0 += k0; x1 += k1 + 3u;
  TFR(17u) TFR(29u) TFR(16u) TFR(24u)  x0 += k1; x1 += k2 + 4u;
  TFR(13u) TFR(15u) TFR(26u) TFR(6u)   x0 += k2; x1 += k0 + 5u;
#undef TFR
  o0 = x0; o1 = x1;
}

// pack score+index so that u64 max == (higher score, then lower index)
__device__ __forceinline__ unsigned long long packCand(uint32_t bits, uint32_t pix){
  float f = __uint_as_float((bits >> 9) | 0x3f800000u) - 1.0f;  // jax uniform [0,1)
  uint32_t u = __float_as_uint(f) ^ 0x80000000u;                // monotone map (f>=0)
  return ((unsigned long long)u << 32) | (unsigned long long)(0xFFFFFFFFu - pix);
}

// sorted-descending 10-element list, sentinel 0
__device__ __forceinline__ void t10_insert(unsigned long long* l, unsigned long long c){
  if (c > l[9]) {
    l[9] = c;
#pragma unroll
    for (int i = 9; i > 0; --i){
      unsigned long long a = l[i-1], b2 = l[i];
      if (b2 > a){ l[i-1] = b2; l[i] = a; }
    }
  }
}

// ---- K1: stream x once: IGN fill + hist partials + dual-key threefry hit detection ----
// Hits stored to private per-block global segments with plain stores (no global atomics).
__global__ __launch_bounds__(256, 8)
void k1_main(const float* __restrict__ x, int* __restrict__ out){
  const int blk = blockIdx.x;
  const int b = blk >> 3, j8 = blk & 7;     // 8 blocks per image, 8192 px each
  const int tid = threadIdx.x;
  const float4* x4 = (const float4*)(x + (size_t)b * NPIX);
  int* meta = out + (size_t)b * NPIX;
  int4* o4 = (int4*)meta;

  __shared__ uint32_t histR[1024];          // 256 bins x 4 lane-columns (conflict spread)
  __shared__ uint32_t s_kw[4];
  __shared__ int s_lcnt[2];
#pragma unroll
  for (int k = 0; k < 4; ++k) histR[tid + 256*k] = 0u;
  if (tid < 2){
    uint32_t o0, o1;
    tf2x32(0u, 1u, 0u, (uint32_t)(2*b + tid), o0, o1);
    s_kw[2*tid] = o0; s_kw[2*tid+1] = o1;
    s_lcnt[tid] = 0;
  }
  __syncthreads();

  const uint32_t fk0 = s_kw[0], fk1 = s_kw[1], bk0 = s_kw[2], bk1 = s_kw[3];
  const int4 f4 = make_int4(IGN, IGN, IGN, IGN);
  const uint32_t c4 = (uint32_t)(tid & 3);
#pragma unroll
  for (int jj = 0; jj < 8; ++jj){
    int i4 = j8*2048 + jj*256 + tid;        // global float4 / out-int4 index
    float4 v = x4[i4];
    uint32_t u0 = (uint32_t)min(max((int)floorf(v.x*255.0f),0),255);
    uint32_t u1 = (uint32_t)min(max((int)floorf(v.y*255.0f),0),255);
    uint32_t u2 = (uint32_t)min(max((int)floorf(v.z*255.0f),0),255);
    uint32_t u3 = (uint32_t)min(max((int)floorf(v.w*255.0f),0),255);
    atomicAdd(&histR[(u0<<2)|c4],1u); atomicAdd(&histR[(u1<<2)|c4],1u);
    atomicAdd(&histR[(u2<<2)|c4],1u); atomicAdd(&histR[(u3<<2)|c4],1u);
    if (i4 >= SCRI4) o4[i4] = f4;           // IGN, skipping scratch ints 0..4095
    uint32_t pix0 = (uint32_t)(4*i4);
#pragma unroll
    for (int s = 0; s < 4; ++s){
      uint32_t pix = pix0 + (uint32_t)s;
      uint32_t a0, a1, c0, c1;
      tf2x32(fk0, fk1, 0u, pix, a0, a1);    // two independent chains -> issue-slot ILP
      tf2x32(bk0, bk1, 0u, pix, c0, c1);
      if ((a0 ^ a1) >= 0xFF000000u){        // top 1/256 slice, mantissa-aligned cut
        int idx = atomicAdd(&s_lcnt[0], 1);
        if (idx < SEGC) meta[FGSEG + j8*SEGC + idx] = (int)pix;
      }
      if ((c0 ^ c1) >= 0xFF000000u){
        int idx = atomicAdd(&s_lcnt[1], 1);
        if (idx < SEGC) meta[BGSEG + j8*SEGC + idx] = (int)pix;
      }
    }
  }
  __syncthreads();
  uint32_t s = histR[4*tid] + histR[4*tid+1] + histR[4*tid+2] + histR[4*tid+3];
  meta[HPART + j8*256 + tid] = (int)s;      // plain store
  if (tid < 2) meta[(tid ? CNTB : CNTF) + j8] = s_lcnt[tid];  // raw count (may > SEGC)
}

// ---- K2: thresholds (scan->Otsu->Li), candidate filter, top-10, scratch fill, patches ----
__global__ __launch_bounds__(256, 2)
void k2_final(const float* __restrict__ x, int* __restrict__ out){
  const int b = blockIdx.x;
  const int tid = threadIdx.x;
  int* meta = out + (size_t)b * NPIX;
  int* outb = meta;
  const float* img = x + (size_t)b * NPIX;

  __shared__ float csum[256], cvsum[256];
  __shared__ int s_imin, s_qthr, s_nroi;
  __shared__ unsigned long long s_best;
  __shared__ uint32_t s_kw[4];
  __shared__ int s_cand[2][GCAP];
  __shared__ int s_cc[2], s_ovf[2], s_fail[2], s_np[2];
  __shared__ unsigned long long s_top[2][64][10];
  __shared__ unsigned long long s_top2[2][8][10];
  __shared__ int s_pr[2][10], s_pc[2][10];

  if (tid == 0){ s_imin = 255; s_best = 0ull; }
  if (tid < 2){
    uint32_t o0, o1;
    tf2x32(0u, 1u, 0u, (uint32_t)(2*b + tid), o0, o1);
    s_kw[2*tid] = o0; s_kw[2*tid+1] = o1;
    s_cc[tid] = 0;
  }
  __syncthreads();

  // ---- histogram sum + exact-integer fp32 scans (bit-exact vs jnp.cumsum) ----
  int h = 0;
#pragma unroll
  for (int j = 0; j < 8; ++j) h += meta[HPART + j*256 + tid];
  if (h) atomicMin(&s_imin, tid);
  __syncthreads();
  const float img_min = (float)s_imin;

  csum[tid]  = (float)h;
  cvsum[tid] = (float)h * ((float)tid - img_min);
  __syncthreads();
  for (int off = 1; off < 256; off <<= 1){
    float a = 0.f, c2 = 0.f;
    if (tid >= off){ a = csum[tid-off]; c2 = cvsum[tid-off]; }
    __syncthreads();
    if (tid >= off){ csum[tid] += a; cvsum[tid] += c2; }
    __syncthreads();
  }

  // ---- Otsu: per-bin var_b + 64-bit argmax (first max wins) ----
  {
    float s_tot_o = cvsum[255] + img_min * csum[255];
    if (tid < 255){
      float w0 = csum[tid];
      float w1 = 65536.0f - w0;
      float cs = cvsum[tid] + img_min * csum[tid];
      float m0 = cs / fmaxf(w0, 1e-12f);
      float m1 = (s_tot_o - cs) / fmaxf(w1, 1e-12f);
      float d = m0 - m1;
      float vb = (w0*w1) * (d*d);
      unsigned long long pk =
        ((unsigned long long)__float_as_uint(vb) << 32) | (unsigned long long)(255 - tid);
      atomicMax(&s_best, pk);
    }
  }
  __syncthreads();

  // ---- Li iteration (serial, tiny) ----
  if (tid == 0){
    int bestIdx = 255 - (int)(s_best & 0xFFFFFFFFull);
    float otsu = fminf(fmaxf((float)bestIdx, 1.0f), 254.0f);
    float n_tot = csum[255], s_tot = cvsum[255];
    float t_curr = otsu - img_min, t_prev = t_curr + 10.0f;
    int it = 0;
    while (fabsf(t_curr - t_prev) > 0.5f && it < 64){
      int idx = min(max((int)floorf(t_curr + img_min), 0), 255);
      float n_back = csum[idx], s_back = cvsum[idx];
      float n_fore = n_tot - n_back, s_fore = s_tot - s_back;
      float mean_back = (n_back > 0.0f) ? (s_back / fmaxf(n_back, 1.0f)) : 0.0f;
      float mean_fore = s_fore / fmaxf(n_fore, 1.0f);
      float t_next = (mean_back - mean_fore) /
                     (logf(fmaxf(mean_back, 1e-12f)) - logf(fmaxf(mean_fore, 1e-12f)));
      if (mean_back < 1e-12f) t_next = mean_fore * 0.5f;
      t_prev = t_curr; t_curr = t_next; ++it;
    }
    float lit = t_curr + img_min;
    // integer threshold: for integer q, (float)q > lit <=> q >= floor(lit)+1
    // NaN lit (degenerate image): predicate false for all q -> qthr=256
    int qthr;
    if (!(lit == lit)) qthr = 256;
    else               qthr = (int)floorf(lit) + 1;
    s_qthr = qthr;
    int nlo = (qthr <= 0) ? 0 : (int)csum[min(qthr, 256) - 1];
    s_nroi = NPIX - nlo;               // exact count(q > lit)
  }
  if (tid < 2){                        // overflow pre-check (list completeness)
    int gc = 0, ovf = 0;
#pragma unroll
    for (int j = 0; j < 8; ++j){
      int c = meta[(tid ? CNTB : CNTF) + j];
      gc += c; if (c > SEGC) ovf = 1;
    }
    s_ovf[tid] = ovf | (gc > GCAP);
  }
  __syncthreads();

  // ---- filter key-hit candidates by region membership (exact counts) ----
  const int qthr = s_qthr;
#pragma unroll
  for (int r2 = 0; r2 < 2; ++r2){
    for (int i = tid; i < GCAP; i += 256){
      int j = i / SEGC, k = i - j*SEGC;
      int cnt = min(meta[(r2 ? CNTB : CNTF) + j], SEGC);
      if (k < cnt){
        uint32_t pix = (uint32_t)meta[(r2 ? BGSEG : FGSEG) + i];
        float v = img[pix];
        int q = min(max((int)floorf(v*255.0f),0),255);
        bool roi = (q >= qthr);
        if (roi == (r2 == 0)){
          int idx = atomicAdd(&s_cc[r2], 1);
          s_cand[r2][idx] = (int)pix;
        }
      }
    }
  }
  __syncthreads();
  if (tid < 2){
    int rs = tid ? (NPIX - s_nroi) : s_nroi;
    int cc = s_cc[tid];
    s_fail[tid] = s_ovf[tid] || (cc < 10 && cc != rs);
  }
  __syncthreads();

  // ---- per-lane top-10 (wave 0 -> fg, wave 1 -> bg); fallback rescans floats ----
  const int wv = tid >> 6, lane = tid & 63;
  if (wv < 2){
    const int r2 = wv;
    unsigned long long t[10];
#pragma unroll
    for (int i = 0; i < 10; ++i) t[i] = 0ull;
    const uint32_t kk0 = s_kw[2*r2], kk1 = s_kw[2*r2+1];
    if (!s_fail[r2]){
      int n = s_cc[r2];
      for (int i = lane; i < n; i += 64){
        uint32_t pix = (uint32_t)s_cand[r2][i];
        uint32_t o0, o1; tf2x32(kk0, kk1, 0u, pix, o0, o1);
        t10_insert(t, packCand(o0 ^ o1, pix));
      }
    } else {
      for (int k = 0; k < 1024; ++k){
        uint32_t pix = (uint32_t)(lane + 64*k);
        float v = img[pix];
        int q = min(max((int)floorf(v*255.0f),0),255);
        bool roi = (q >= qthr);
        if (roi == (r2 == 0)){
          uint32_t o0, o1; tf2x32(kk0, kk1, 0u, pix, o0, o1);
          t10_insert(t, packCand(o0 ^ o1, pix));
        }
      }
    }
#pragma unroll
    for (int i = 0; i < 10; ++i) s_top[r2][lane][i] = t[i];
  }
  __syncthreads();
  // ---- merge 64 -> 8 ----
  if (wv < 2 && lane < 8){
    unsigned long long t[10];
#pragma unroll
    for (int i = 0; i < 10; ++i) t[i] = 0ull;
    for (int l2 = 0; l2 < 8; ++l2)
#pragma unroll
      for (int i = 0; i < 10; ++i) t10_insert(t, s_top[wv][lane*8 + l2][i]);
#pragma unroll
    for (int i = 0; i < 10; ++i) s_top2[wv][lane][i] = t[i];
  }
  __syncthreads();
  // ---- merge 8 -> 1, extract points ----
  if (wv < 2 && lane == 0){
    unsigned long long t[10];
#pragma unroll
    for (int i = 0; i < 10; ++i) t[i] = 0ull;
    for (int l2 = 0; l2 < 8; ++l2)
#pragma unroll
      for (int i = 0; i < 10; ++i) t10_insert(t, s_top2[wv][l2][i]);
    int np = 0;
    for (int i = 0; i < 10; ++i){
      if (t[i]){
        uint32_t pix = 0xFFFFFFFFu - (uint32_t)(t[i] & 0xFFFFFFFFull);
        s_pr[wv][np] = (int)(pix >> 8);
        s_pc[wv][np] = (int)(pix & 255u);
        ++np;
      }
    }
    s_np[wv] = np;
  }
  __syncthreads();

  // ---- overwrite scratch ints 0..4095 with IGN (candidates already consumed) ----
  const int4 f4 = make_int4(IGN, IGN, IGN, IGN);
#pragma unroll
  for (int k = 0; k < 4; ++k)
    ((int4*)meta)[tid + 256*k] = f4;
  __syncthreads();

  // ---- write dilated seed patches (<=180 px); duplicates write identical values ----
  const int nfg = s_np[0], nbg = s_np[1];
  const int npts = nfg + nbg;
  if (tid < npts*9){
    int k = tid / 9, d = tid - k*9;
    int pr = (k < nfg) ? s_pr[0][k] : s_pr[1][k - nfg];
    int pc = (k < nfg) ? s_pc[0][k] : s_pc[1][k - nfg];
    pr += d/3 - 1; pc += d%3 - 1;
    if (pr >= 0 && pr < 256 && pc >= 0 && pc < 256){
      bool fgd = false, bgd = false;
      for (int i = 0; i < nfg; ++i) fgd |= (abs(pr - s_pr[0][i]) <= 1) && (abs(pc - s_pc[0][i]) <= 1);
      for (int i = 0; i < nbg; ++i) bgd |= (abs(pr - s_pr[1][i]) <= 1) && (abs(pc - s_pc[1][i]) <= 1);
      int val = (fgd && bgd) ? IGN : (fgd ? 1 : 0);
      outb[pr*256 + pc] = val;
    }
  }
}

extern "C" void kernel_launch(void* const* d_in, const int* in_sizes, int n_in,
                              void* d_out, int out_size, void* d_ws, size_t ws_size,
                              hipStream_t stream) {
  const float* x = (const float*)d_in[0];
  int* out = (int*)d_out;
  int B = in_sizes[0] / NPIX;
  k1_main <<<8*B, 256, 0, stream>>>(x, out);
  k2_final<<<B,   256, 0, stream>>>(x, out);
}

// Round 6
// 184.121 us; speedup vs baseline: 1.0906x; 1.0406x over previous
//
#include <hip/hip_runtime.h>
#include <stdint.h>

#define NPIX 65536
#define IGN (-255)
#define CAP 768          // LDS candidate list capacity per region (mean ~128, +32sigma)
// per-image scratch layout inside out[b*NPIX + ...] (ints 0..18431 = rows 0..71)
//   ints 0..16383      packed u8 image (4 px/int, little-endian)
#define HPART 16384      // 2048: 8 x 256 per-block hist partials; ends 18432
#define SCRI4 4608       // scratch size in int4 (ints 0..18431)

// ---------------- threefry2x32 (exact JAX partitionable implementation) ----------------
__device__ __forceinline__ uint32_t rotl32(uint32_t v, uint32_t r){ return (v<<r)|(v>>(32u-r)); }

__device__ __forceinline__ void tf2x32(uint32_t k0, uint32_t k1, uint32_t x0, uint32_t x1,
                                       uint32_t &o0, uint32_t &o1){
  uint32_t k2 = k0 ^ k1 ^ 0x1BD11BDAu;
  x0 += k0; x1 += k1;
#define TFR(r) { x0 += x1; x1 = rotl32(x1,(r)); x1 ^= x0; }
  TFR(13u) TFR(15u) TFR(26u) TFR(6u)   x0 += k1; x1 += k2 + 1u;
  TFR(17u) TFR(29u) TFR(16u) TFR(24u)  x0 += k2; x1 += k0 + 2u;
  TFR(13u) TFR(15u) TFR(26u) TFR(6u)   x0 += k0; x1 += k1 + 3u;
  TFR(17u) TFR(29u) TFR(16u) TFR(24u)  x0 += k1; x1 += k2 + 4u;
  TFR(13u) TFR(15u) TFR(26u) TFR(6u)   x0 += k2; x1 += k0 + 5u;
#undef TFR
  o0 = x0; o1 = x1;
}

// pack score+index so that u64 max == (higher score, then lower index)
__device__ __forceinline__ unsigned long long packCand(uint32_t bits, uint32_t pix){
  float f = __uint_as_float((bits >> 9) | 0x3f800000u) - 1.0f;  // jax uniform [0,1)
  uint32_t u = __float_as_uint(f) ^ 0x80000000u;                // monotone map (f>=0)
  return ((unsigned long long)u << 32) | (unsigned long long)(0xFFFFFFFFu - pix);
}

// sorted-descending 10-element list, sentinel 0
__device__ __forceinline__ void t10_insert(unsigned long long* l, unsigned long long c){
  if (c > l[9]) {
    l[9] = c;
#pragma unroll
    for (int i = 9; i > 0; --i){
      unsigned long long a = l[i-1], b2 = l[i];
      if (b2 > a){ l[i-1] = b2; l[i] = a; }
    }
  }
}

// ------- K1: quantize->u8 scratch, IGN fill (non-scratch), per-block hist partials -------
__global__ __launch_bounds__(256, 8)
void k1_stream(const float* __restrict__ x, int* __restrict__ out){
  const int blk = blockIdx.x;
  const int b = blk >> 3, j8 = blk & 7;     // 8 blocks per image, 8192 px each
  const int tid = threadIdx.x;
  const float4* x4 = (const float4*)(x + (size_t)b * NPIX);
  int* base = out + (size_t)b * NPIX;
  int4* o4 = (int4*)base;

  __shared__ uint32_t histR[1024];          // 256 bins x 4 lane-columns (conflict spread)
#pragma unroll
  for (int k = 0; k < 4; ++k) histR[tid + 256*k] = 0u;
  __syncthreads();

  const int4 f4 = make_int4(IGN, IGN, IGN, IGN);
  const uint32_t c4 = (uint32_t)(tid & 3);
#pragma unroll
  for (int jj = 0; jj < 8; ++jj){
    int i4 = j8*2048 + jj*256 + tid;        // global float4 / packed-int / out-int4 index
    float4 v = x4[i4];
    uint32_t u0 = (uint32_t)min(max((int)floorf(v.x*255.0f),0),255);
    uint32_t u1 = (uint32_t)min(max((int)floorf(v.y*255.0f),0),255);
    uint32_t u2 = (uint32_t)min(max((int)floorf(v.z*255.0f),0),255);
    uint32_t u3 = (uint32_t)min(max((int)floorf(v.w*255.0f),0),255);
    base[i4] = (int)(u0 | (u1<<8) | (u2<<16) | (u3<<24));   // u8 scratch (ints 0..16383)
    if (i4 >= SCRI4) o4[i4] = f4;           // IGN, skipping scratch ints 0..18431
    atomicAdd(&histR[(u0<<2)|c4],1u); atomicAdd(&histR[(u1<<2)|c4],1u);
    atomicAdd(&histR[(u2<<2)|c4],1u); atomicAdd(&histR[(u3<<2)|c4],1u);
  }
  __syncthreads();
  uint32_t s = histR[4*tid] + histR[4*tid+1] + histR[4*tid+2] + histR[4*tid+3];
  base[HPART + j8*256 + tid] = (int)s;      // plain store: no zeroing pass needed
}

// ---- K2: threshold once (scan->Otsu->Li), 1-key score from u8, LDS candidates, ----
// ----     wave-parallel top-10, scratch IGN-fill, dilated patches                ----
__global__ __launch_bounds__(1024, 4)
void k2_final(int* __restrict__ out){
  const int b = blockIdx.x;
  const int tid = threadIdx.x;
  int* meta = out + (size_t)b * NPIX;
  int* outb = meta;

  __shared__ float csum[256], cvsum[256];
  __shared__ int s_imin, s_qthr, s_nroi;
  __shared__ unsigned long long s_best;
  __shared__ uint32_t s_kw[4];
  __shared__ unsigned long long buf[2][CAP];
  __shared__ int s_cnt[2], s_fail[2], s_np[2];
  __shared__ unsigned long long s_top[2][64][10];
  __shared__ unsigned long long s_top2[2][8][10];
  __shared__ int s_pr[2][10], s_pc[2][10];

  if (tid == 0){ s_imin = 255; s_best = 0ull; }
  if (tid < 2){
    uint32_t o0, o1;
    tf2x32(0u, 1u, 0u, (uint32_t)(2*b + tid), o0, o1);
    s_kw[2*tid] = o0; s_kw[2*tid+1] = o1;
    s_cnt[tid] = 0;
  }
  __syncthreads();

  // ---- histogram sum + exact-integer fp32 scans (bit-exact vs jnp.cumsum) ----
  int h = 0;
  if (tid < 256){
#pragma unroll
    for (int j = 0; j < 8; ++j) h += meta[HPART + j*256 + tid];
    if (h) atomicMin(&s_imin, tid);
  }
  __syncthreads();
  const float img_min = (float)s_imin;
  if (tid < 256){
    csum[tid]  = (float)h;
    cvsum[tid] = (float)h * ((float)tid - img_min);
  }
  __syncthreads();
  for (int off = 1; off < 256; off <<= 1){
    float a = 0.f, c2 = 0.f;
    if (tid < 256 && tid >= off){ a = csum[tid-off]; c2 = cvsum[tid-off]; }
    __syncthreads();
    if (tid < 256 && tid >= off){ csum[tid] += a; cvsum[tid] += c2; }
    __syncthreads();
  }

  // ---- Otsu: per-bin var_b + 64-bit argmax (first max wins) ----
  {
    float s_tot_o = cvsum[255] + img_min * csum[255];
    if (tid < 255){
      float w0 = csum[tid];
      float w1 = 65536.0f - w0;
      float cs = cvsum[tid] + img_min * csum[tid];
      float m0 = cs / fmaxf(w0, 1e-12f);
      float m1 = (s_tot_o - cs) / fmaxf(w1, 1e-12f);
      float d = m0 - m1;
      float vb = (w0*w1) * (d*d);
      unsigned long long pk =
        ((unsigned long long)__float_as_uint(vb) << 32) | (unsigned long long)(255 - tid);
      atomicMax(&s_best, pk);
    }
  }
  __syncthreads();

  // ---- Li iteration (serial, tiny) ----
  if (tid == 0){
    int bestIdx = 255 - (int)(s_best & 0xFFFFFFFFull);
    float otsu = fminf(fmaxf((float)bestIdx, 1.0f), 254.0f);
    float n_tot = csum[255], s_tot = cvsum[255];
    float t_curr = otsu - img_min, t_prev = t_curr + 10.0f;
    int it = 0;
    while (fabsf(t_curr - t_prev) > 0.5f && it < 64){
      int idx = min(max((int)floorf(t_curr + img_min), 0), 255);
      float n_back = csum[idx], s_back = cvsum[idx];
      float n_fore = n_tot - n_back, s_fore = s_tot - s_back;
      float mean_back = (n_back > 0.0f) ? (s_back / fmaxf(n_back, 1.0f)) : 0.0f;
      float mean_fore = s_fore / fmaxf(n_fore, 1.0f);
      float t_next = (mean_back - mean_fore) /
                     (logf(fmaxf(mean_back, 1e-12f)) - logf(fmaxf(mean_fore, 1e-12f)));
      if (mean_back < 1e-12f) t_next = mean_fore * 0.5f;
      t_prev = t_curr; t_curr = t_next; ++it;
    }
    float lit = t_curr + img_min;
    // integer threshold: for integer q, (float)q > lit <=> q >= floor(lit)+1
    // NaN lit (degenerate image): predicate false for all q -> qthr=256
    int qthr;
    if (!(lit == lit)) qthr = 256;
    else               qthr = (int)floorf(lit) + 1;
    s_qthr = qthr;
    int nlo = (qthr <= 0) ? 0 : (int)csum[min(qthr, 256) - 1];
    s_nroi = NPIX - nlo;               // exact count(q > lit)
  }
  __syncthreads();

  // ---- scoring: 1 threefry per pixel (region key), LDS candidate push ----
  const int qthr = s_qthr;
  const uint32_t fk0 = s_kw[0], fk1 = s_kw[1], bk0 = s_kw[2], bk1 = s_kw[3];
  const int4* u4 = (const int4*)meta;       // packed u8 image as int4 (16 px each)
  // issue all 4 loads up-front (64 px / thread)
  int4 w0 = u4[tid], w1 = u4[tid + 1024], w2 = u4[tid + 2048], w3 = u4[tid + 3072];
#pragma unroll
  for (int k = 0; k < 4; ++k){
    int4 w = (k == 0) ? w0 : (k == 1) ? w1 : (k == 2) ? w2 : w3;
    uint32_t pb = (uint32_t)(16*(tid + 1024*k));
    const uint32_t words[4] = {(uint32_t)w.x,(uint32_t)w.y,(uint32_t)w.z,(uint32_t)w.w};
#pragma unroll
    for (int m = 0; m < 4; ++m){
      uint32_t pk = words[m];
#pragma unroll
      for (int s = 0; s < 4; ++s){
        int q = (int)((pk >> (8*s)) & 255u);
        bool r = (q >= qthr);
        uint32_t pix = pb + (uint32_t)(4*m + s);
        uint32_t o0, o1;
        tf2x32(r ? fk0 : bk0, r ? fk1 : bk1, 0u, pix, o0, o1);
        uint32_t bits = o0 ^ o1;
        if (bits >= 0xFF000000u){         // top 1/256 slice, mantissa-aligned cut
          int r2 = r ? 0 : 1;
          int idx = atomicAdd(&s_cnt[r2], 1);
          if (idx < CAP) buf[r2][idx] = packCand(bits, pix);
        }
      }
    }
  }
  __syncthreads();

  // ---- validity: need (collected >= 10) or (collected == region size); no overflow ----
  if (tid < 2){
    int rs = tid ? (NPIX - s_nroi) : s_nroi;
    int cc = s_cnt[tid];
    s_fail[tid] = (cc > CAP) || (cc < 10 && cc != rs);
  }
  __syncthreads();

  // ---- per-lane top-10 (wave 0 -> fg, wave 1 -> bg); fallback rescans u8 ----
  const int wv = tid >> 6, lane = tid & 63;
  if (wv < 2){
    const int r2 = wv;
    unsigned long long t[10];
#pragma unroll
    for (int i = 0; i < 10; ++i) t[i] = 0ull;
    if (!s_fail[r2]){
      int n = min(s_cnt[r2], CAP);
      for (int i = lane; i < n; i += 64) t10_insert(t, buf[r2][i]);
    } else {
      const uint32_t kk0 = s_kw[2*r2], kk1 = s_kw[2*r2+1];
      for (int k = 0; k < 1024; ++k){
        uint32_t pix = (uint32_t)(lane + 64*k);
        int q = (int)(((uint32_t)meta[pix >> 2] >> (8*(pix & 3u))) & 255u);
        bool r = (q >= qthr);
        if (r == (r2 == 0)){
          uint32_t o0, o1; tf2x32(kk0, kk1, 0u, pix, o0, o1);
          t10_insert(t, packCand(o0 ^ o1, pix));
        }
      }
    }
#pragma unroll
    for (int i = 0; i < 10; ++i) s_top[r2][lane][i] = t[i];
  }
  __syncthreads();
  // ---- merge 64 -> 8 ----
  if (wv < 2 && lane < 8){
    unsigned long long t[10];
#pragma unroll
    for (int i = 0; i < 10; ++i) t[i] = 0ull;
    for (int l2 = 0; l2 < 8; ++l2)
#pragma unroll
      for (int i = 0; i < 10; ++i) t10_insert(t, s_top[wv][lane*8 + l2][i]);
#pragma unroll
    for (int i = 0; i < 10; ++i) s_top2[wv][lane][i] = t[i];
  }
  __syncthreads();
  // ---- merge 8 -> 1, extract points ----
  if (wv < 2 && lane == 0){
    unsigned long long t[10];
#pragma unroll
    for (int i = 0; i < 10; ++i) t[i] = 0ull;
    for (int l2 = 0; l2 < 8; ++l2)
#pragma unroll
      for (int i = 0; i < 10; ++i) t10_insert(t, s_top2[wv][l2][i]);
    int np = 0;
    for (int i = 0; i < 10; ++i){
      if (t[i]){
        uint32_t pix = 0xFFFFFFFFu - (uint32_t)(t[i] & 0xFFFFFFFFull);
        s_pr[wv][np] = (int)(pix >> 8);
        s_pc[wv][np] = (int)(pix & 255u);
        ++np;
      }
    }
    s_np[wv] = np;
  }
  __syncthreads();

  // ---- overwrite scratch ints 0..18431 with IGN (candidates already consumed) ----
  const int4 f4 = make_int4(IGN, IGN, IGN, IGN);
#pragma unroll
  for (int k = 0; k < 5; ++k){
    int idx = tid + 1024*k;
    if (idx < SCRI4) ((int4*)meta)[idx] = f4;
  }
  __syncthreads();

  // ---- write dilated seed patches (<=180 px); duplicates write identical values ----
  const int nfg = s_np[0], nbg = s_np[1];
  const int npts = nfg + nbg;
  if (tid < npts*9){
    int k = tid / 9, d = tid - k*9;
    int pr = (k < nfg) ? s_pr[0][k] : s_pr[1][k - nfg];
    int pc = (k < nfg) ? s_pc[0][k] : s_pc[1][k - nfg];
    pr += d/3 - 1; pc += d%3 - 1;
    if (pr >= 0 && pr < 256 && pc >= 0 && pc < 256){
      bool fgd = false, bgd = false;
      for (int i = 0; i < nfg; ++i) fgd |= (abs(pr - s_pr[0][i]) <= 1) && (abs(pc - s_pc[0][i]) <= 1);
      for (int i = 0; i < nbg; ++i) bgd |= (abs(pr - s_pr[1][i]) <= 1) && (abs(pc - s_pc[1][i]) <= 1);
      int val = (fgd && bgd) ? IGN : (fgd ? 1 : 0);
      outb[pr*256 + pc] = val;
    }
  }
}

extern "C" void kernel_launch(void* const* d_in, const int* in_sizes, int n_in,
                              void* d_out, int out_size, void* d_ws, size_t ws_size,
                              hipStream_t stream) {
  const float* x = (const float*)d_in[0];
  int* out = (int*)d_out;
  int B = in_sizes[0] / NPIX;
  k1_stream<<<8*B, 256, 0, stream>>>(x, out);
  k2_final <<<B,  1024, 0, stream>>>(out);
}

// Round 7
// 177.709 us; speedup vs baseline: 1.1299x; 1.0361x over previous
//
#include <hip/hip_runtime.h>
#include <stdint.h>

#define NPIX 65536
#define IGN (-255)
#define CAP 768          // LDS candidate list capacity per region (mean ~128, +32sigma)
// per-image scratch layout inside out[b*NPIX + ...] (ints 0..18431 = rows 0..71)
//   ints 0..16383      packed u8 image (4 px/int, little-endian)
#define HPART 16384      // 2048: 8 x 256 per-block hist partials; ends 18432
#define SCRI4 4608       // scratch size in int4 (ints 0..18431)

// ---------------- threefry2x32 (exact JAX partitionable implementation) ----------------
__device__ __forceinline__ uint32_t rotl32(uint32_t v, uint32_t r){ return (v<<r)|(v>>(32u-r)); }

__device__ __forceinline__ void tf2x32(uint32_t k0, uint32_t k1, uint32_t x0, uint32_t x1,
                                       uint32_t &o0, uint32_t &o1){
  uint32_t k2 = k0 ^ k1 ^ 0x1BD11BDAu;
  x0 += k0; x1 += k1;
#define TFR(r) { x0 += x1; x1 = rotl32(x1,(r)); x1 ^= x0; }
  TFR(13u) TFR(15u) TFR(26u) TFR(6u)   x0 += k1; x1 += k2 + 1u;
  TFR(17u) TFR(29u) TFR(16u) TFR(24u)  x0 += k2; x1 += k0 + 2u;
  TFR(13u) TFR(15u) TFR(26u) TFR(6u)   x0 += k0; x1 += k1 + 3u;
  TFR(17u) TFR(29u) TFR(16u) TFR(24u)  x0 += k1; x1 += k2 + 4u;
  TFR(13u) TFR(15u) TFR(26u) TFR(6u)   x0 += k2; x1 += k0 + 5u;
#undef TFR
  o0 = x0; o1 = x1;
}

// pack score+index so that u64 max == (higher score, then lower index)
__device__ __forceinline__ unsigned long long packCand(uint32_t bits, uint32_t pix){
  float f = __uint_as_float((bits >> 9) | 0x3f800000u) - 1.0f;  // jax uniform [0,1)
  uint32_t u = __float_as_uint(f) ^ 0x80000000u;                // monotone map (f>=0)
  return ((unsigned long long)u << 32) | (unsigned long long)(0xFFFFFFFFu - pix);
}

// sorted-descending 10-element list, sentinel 0
__device__ __forceinline__ void t10_insert(unsigned long long* l, unsigned long long c){
  if (c > l[9]) {
    l[9] = c;
#pragma unroll
    for (int i = 9; i > 0; --i){
      unsigned long long a = l[i-1], b2 = l[i];
      if (b2 > a){ l[i-1] = b2; l[i] = a; }
    }
  }
}

// ------- K1: quantize->u8 scratch, IGN fill (non-scratch), per-block hist partials -------
__global__ __launch_bounds__(256, 8)
void k1_stream(const float* __restrict__ x, int* __restrict__ out){
  const int blk = blockIdx.x;
  const int b = blk >> 3, j8 = blk & 7;     // 8 blocks per image, 8192 px each
  const int tid = threadIdx.x;
  const float4* x4 = (const float4*)(x + (size_t)b * NPIX);
  int* base = out + (size_t)b * NPIX;
  int4* o4 = (int4*)base;

  __shared__ uint32_t histR[1024];          // 256 bins x 4 lane-columns (conflict spread)
#pragma unroll
  for (int k = 0; k < 4; ++k) histR[tid + 256*k] = 0u;
  __syncthreads();

  const int4 f4 = make_int4(IGN, IGN, IGN, IGN);
  const uint32_t c4 = (uint32_t)(tid & 3);
#pragma unroll
  for (int jj = 0; jj < 8; ++jj){
    int i4 = j8*2048 + jj*256 + tid;        // global float4 / packed-int / out-int4 index
    float4 v = x4[i4];
    uint32_t u0 = (uint32_t)min(max((int)floorf(v.x*255.0f),0),255);
    uint32_t u1 = (uint32_t)min(max((int)floorf(v.y*255.0f),0),255);
    uint32_t u2 = (uint32_t)min(max((int)floorf(v.z*255.0f),0),255);
    uint32_t u3 = (uint32_t)min(max((int)floorf(v.w*255.0f),0),255);
    base[i4] = (int)(u0 | (u1<<8) | (u2<<16) | (u3<<24));   // u8 scratch (ints 0..16383)
    if (i4 >= SCRI4) o4[i4] = f4;           // IGN, skipping scratch ints 0..18431
    atomicAdd(&histR[(u0<<2)|c4],1u); atomicAdd(&histR[(u1<<2)|c4],1u);
    atomicAdd(&histR[(u2<<2)|c4],1u); atomicAdd(&histR[(u3<<2)|c4],1u);
  }
  __syncthreads();
  uint32_t s = histR[4*tid] + histR[4*tid+1] + histR[4*tid+2] + histR[4*tid+3];
  base[HPART + j8*256 + tid] = (int)s;      // plain store: no zeroing pass needed
}

// ---- K2: wave-local threshold (shfl scan -> Otsu -> Li), 1-key score from u8 (loop-   ----
// ---- resident code), LDS candidates, wave-parallel top-10, scratch IGN-fill, patches  ----
__global__ __launch_bounds__(1024, 4)
void k2_final(int* __restrict__ out){
  const int b = blockIdx.x;
  const int tid = threadIdx.x;
  int* meta = out + (size_t)b * NPIX;
  int* outb = meta;

  __shared__ float csum[256], cvsum[256];
  __shared__ int s_qthr, s_nroi;
  __shared__ uint32_t s_kw[4];
  __shared__ unsigned long long buf[2][CAP];
  __shared__ int s_cnt[2], s_fail[2], s_np[2];
  __shared__ unsigned long long s_top[2][64][10];
  __shared__ unsigned long long s_top2[2][8][10];
  __shared__ int s_pr[2][10], s_pc[2][10];

  if (tid < 2){
    uint32_t o0, o1;
    tf2x32(0u, 1u, 0u, (uint32_t)(2*b + tid), o0, o1);
    s_kw[2*tid] = o0; s_kw[2*tid+1] = o1;
    s_cnt[tid] = 0;
  }

  // ---- threshold: wave 0 only, shuffle-based (no block barriers inside) ----
  // exactness: all histogram partial sums / weighted sums are integers < 2^24,
  // so fp32 addition in ANY order is bit-identical to jnp.cumsum.
  if (tid < 64){
    const int lane = tid;
    int h0 = 0, h1 = 0, h2 = 0, h3 = 0;
    for (int j = 0; j < 8; ++j){
      const int4 p = *(const int4*)&meta[HPART + j*256 + 4*lane];
      h0 += p.x; h1 += p.y; h2 += p.z; h3 += p.w;
    }
    // img_min = first nonzero bin
    int cand = 256;
    if (h3) cand = 4*lane + 3;
    if (h2) cand = 4*lane + 2;
    if (h1) cand = 4*lane + 1;
    if (h0) cand = 4*lane + 0;
    for (int off = 32; off; off >>= 1) cand = min(cand, __shfl_xor(cand, off));
    const float img_min = (float)cand;
    // in-lane inclusive prefix over 4 bins
    float c0 = (float)h0, c1 = c0 + h1, c2 = c1 + h2, c3 = c2 + h3;
    float bv = 4.0f*lane - img_min;
    float v0 = h0*bv;
    float v1 = v0 + h1*(bv + 1.0f);
    float v2 = v1 + h2*(bv + 2.0f);
    float v3 = v2 + h3*(bv + 3.0f);
    // wave inclusive scan of lane totals
    float cc = c3, vv = v3;
    for (int off = 1; off < 64; off <<= 1){
      float a = __shfl_up(cc, off), b2 = __shfl_up(vv, off);
      if (lane >= off){ cc += a; vv += b2; }
    }
    const float cexc = cc - c3, vexc = vv - v3;
    const float cs0 = cexc+c0, cs1 = cexc+c1, cs2 = cexc+c2, cs3 = cexc+c3;
    const float vs0 = vexc+v0, vs1 = vexc+v1, vs2 = vexc+v2, vs3 = vexc+v3;
    csum[4*lane]   = cs0; csum[4*lane+1]  = cs1;
    csum[4*lane+2] = cs2; csum[4*lane+3]  = cs3;
    cvsum[4*lane]   = vs0; cvsum[4*lane+1] = vs1;
    cvsum[4*lane+2] = vs2; cvsum[4*lane+3] = vs3;
    const float ctot = __shfl(cc, 63), vtot = __shfl(vv, 63);
    // Otsu: per-bin var_b, u64 argmax (first max wins)
    const float s_tot_o = vtot + img_min * ctot;   // == sum(hist*i), exact int
    unsigned long long best = 0ull;
#define OTSU_BIN(CS, VS, J)                                              \
    { int bin = 4*lane + (J);                                            \
      if (bin < 255){                                                    \
        float w0 = (CS);                                                 \
        float w1 = 65536.0f - w0;                                        \
        float cs = (VS) + img_min * (CS);                                \
        float m0 = cs / fmaxf(w0, 1e-12f);                               \
        float m1 = (s_tot_o - cs) / fmaxf(w1, 1e-12f);                   \
        float d = m0 - m1;                                               \
        float vb = (w0*w1) * (d*d);                                      \
        unsigned long long pk =                                          \
          ((unsigned long long)__float_as_uint(vb) << 32) |              \
           (unsigned long long)(255 - bin);                              \
        if (pk > best) best = pk;                                        \
      } }
    OTSU_BIN(cs0, vs0, 0) OTSU_BIN(cs1, vs1, 1)
    OTSU_BIN(cs2, vs2, 2) OTSU_BIN(cs3, vs3, 3)
#undef OTSU_BIN
    for (int off = 32; off; off >>= 1){
      unsigned int hi = (unsigned int)(best >> 32), lo = (unsigned int)best;
      unsigned int hio = (unsigned int)__shfl_xor((int)hi, off);
      unsigned int loo = (unsigned int)__shfl_xor((int)lo, off);
      unsigned long long ob = ((unsigned long long)hio << 32) | loo;
      if (ob > best) best = ob;
    }
    // Li iteration (serial on lane 0, reads LDS csum/cvsum — same-wave ordering)
    if (lane == 0){
      int bestIdx = 255 - (int)(best & 0xFFFFFFFFull);
      float otsu = fminf(fmaxf((float)bestIdx, 1.0f), 254.0f);
      float n_tot = ctot, s_tot = vtot;
      float t_curr = otsu - img_min, t_prev = t_curr + 10.0f;
      int it = 0;
      while (fabsf(t_curr - t_prev) > 0.5f && it < 64){
        int idx = min(max((int)floorf(t_curr + img_min), 0), 255);
        float n_back = csum[idx], s_back = cvsum[idx];
        float n_fore = n_tot - n_back, s_fore = s_tot - s_back;
        float mean_back = (n_back > 0.0f) ? (s_back / fmaxf(n_back, 1.0f)) : 0.0f;
        float mean_fore = s_fore / fmaxf(n_fore, 1.0f);
        float t_next = (mean_back - mean_fore) /
                       (logf(fmaxf(mean_back, 1e-12f)) - logf(fmaxf(mean_fore, 1e-12f)));
        if (mean_back < 1e-12f) t_next = mean_fore * 0.5f;
        t_prev = t_curr; t_curr = t_next; ++it;
      }
      float lit = t_curr + img_min;
      // integer threshold: for integer q, (float)q > lit <=> q >= floor(lit)+1
      // NaN lit (degenerate image): predicate false for all q -> qthr=256
      int qthr;
      if (!(lit == lit)) qthr = 256;
      else               qthr = (int)floorf(lit) + 1;
      s_qthr = qthr;
      int nlo = (qthr <= 0) ? 0 : (int)csum[min(qthr, 256) - 1];
      s_nroi = NPIX - nlo;             // exact count(q > lit)
    }
  }
  __syncthreads();

  // ---- scoring: 1 threefry per pixel (region key), loop-resident code (I$-friendly) ----
  const int qthr = s_qthr;
  const uint32_t fk0 = s_kw[0], fk1 = s_kw[1], bk0 = s_kw[2], bk1 = s_kw[3];
  const int4* u4 = (const int4*)meta;       // packed u8 image as int4 (16 px each)
  for (int k = 0; k < 4; ++k){              // runtime loop: body ~10KB, stays in I$
    int4 w = u4[tid + 1024*k];
    uint32_t pw0 = (uint32_t)(16*(tid + 1024*k));
#pragma unroll
    for (int m = 0; m < 4; ++m){
      uint32_t pk = (m==0)?(uint32_t)w.x:(m==1)?(uint32_t)w.y:(m==2)?(uint32_t)w.z:(uint32_t)w.w;
      uint32_t pb = pw0 + (uint32_t)(4*m);
#pragma unroll
      for (int s = 0; s < 4; ++s){
        int q = (int)((pk >> (8*s)) & 255u);
        bool r = (q >= qthr);
        uint32_t pix = pb + (uint32_t)s;
        uint32_t o0, o1;
        tf2x32(r ? fk0 : bk0, r ? fk1 : bk1, 0u, pix, o0, o1);
        uint32_t bits = o0 ^ o1;
        if (bits >= 0xFF000000u){         // top 1/256 slice, mantissa-aligned cut
          int r2 = r ? 0 : 1;
          int idx = atomicAdd(&s_cnt[r2], 1);
          if (idx < CAP) buf[r2][idx] = packCand(bits, pix);
        }
      }
    }
  }
  __syncthreads();

  // ---- validity: need (collected >= 10) or (collected == region size); no overflow ----
  if (tid < 2){
    int rs = tid ? (NPIX - s_nroi) : s_nroi;
    int cc = s_cnt[tid];
    s_fail[tid] = (cc > CAP) || (cc < 10 && cc != rs);
  }
  __syncthreads();

  // ---- per-lane top-10 (wave 0 -> fg, wave 1 -> bg); fallback rescans u8 ----
  const int wv = tid >> 6, lane = tid & 63;
  if (wv < 2){
    const int r2 = wv;
    unsigned long long t[10];
#pragma unroll
    for (int i = 0; i < 10; ++i) t[i] = 0ull;
    if (!s_fail[r2]){
      int n = min(s_cnt[r2], CAP);
      for (int i = lane; i < n; i += 64) t10_insert(t, buf[r2][i]);
    } else {
      const uint32_t kk0 = s_kw[2*r2], kk1 = s_kw[2*r2+1];
      for (int k = 0; k < 1024; ++k){
        uint32_t pix = (uint32_t)(lane + 64*k);
        int q = (int)(((uint32_t)meta[pix >> 2] >> (8*(pix & 3u))) & 255u);
        bool r = (q >= qthr);
        if (r == (r2 == 0)){
          uint32_t o0, o1; tf2x32(kk0, kk1, 0u, pix, o0, o1);
          t10_insert(t, packCand(o0 ^ o1, pix));
        }
      }
    }
#pragma unroll
    for (int i = 0; i < 10; ++i) s_top[r2][lane][i] = t[i];
  }
  __syncthreads();
  // ---- merge 64 -> 8 ----
  if (wv < 2 && lane < 8){
    unsigned long long t[10];
#pragma unroll
    for (int i = 0; i < 10; ++i) t[i] = 0ull;
    for (int l2 = 0; l2 < 8; ++l2)
#pragma unroll
      for (int i = 0; i < 10; ++i) t10_insert(t, s_top[wv][lane*8 + l2][i]);
#pragma unroll
    for (int i = 0; i < 10; ++i) s_top2[wv][lane][i] = t[i];
  }
  __syncthreads();
  // ---- merge 8 -> 1, extract points ----
  if (wv < 2 && lane == 0){
    unsigned long long t[10];
#pragma unroll
    for (int i = 0; i < 10; ++i) t[i] = 0ull;
    for (int l2 = 0; l2 < 8; ++l2)
#pragma unroll
      for (int i = 0; i < 10; ++i) t10_insert(t, s_top2[wv][l2][i]);
    int np = 0;
    for (int i = 0; i < 10; ++i){
      if (t[i]){
        uint32_t pix = 0xFFFFFFFFu - (uint32_t)(t[i] & 0xFFFFFFFFull);
        s_pr[wv][np] = (int)(pix >> 8);
        s_pc[wv][np] = (int)(pix & 255u);
        ++np;
      }
    }
    s_np[wv] = np;
  }
  __syncthreads();

  // ---- overwrite scratch ints 0..18431 with IGN (candidates already consumed) ----
  const int4 f4 = make_int4(IGN, IGN, IGN, IGN);
#pragma unroll
  for (int k = 0; k < 5; ++k){
    int idx = tid + 1024*k;
    if (idx < SCRI4) ((int4*)meta)[idx] = f4;
  }
  __syncthreads();

  // ---- write dilated seed patches (<=180 px); duplicates write identical values ----
  const int nfg = s_np[0], nbg = s_np[1];
  const int npts = nfg + nbg;
  if (tid < npts*9){
    int k = tid / 9, d = tid - k*9;
    int pr = (k < nfg) ? s_pr[0][k] : s_pr[1][k - nfg];
    int pc = (k < nfg) ? s_pc[0][k] : s_pc[1][k - nfg];
    pr += d/3 - 1; pc += d%3 - 1;
    if (pr >= 0 && pr < 256 && pc >= 0 && pc < 256){
      bool fgd = false, bgd = false;
      for (int i = 0; i < nfg; ++i) fgd |= (abs(pr - s_pr[0][i]) <= 1) && (abs(pc - s_pc[0][i]) <= 1);
      for (int i = 0; i < nbg; ++i) bgd |= (abs(pr - s_pr[1][i]) <= 1) && (abs(pc - s_pc[1][i]) <= 1);
      int val = (fgd && bgd) ? IGN : (fgd ? 1 : 0);
      outb[pr*256 + pc] = val;
    }
  }
}

extern "C" void kernel_launch(void* const* d_in, const int* in_sizes, int n_in,
                              void* d_out, int out_size, void* d_ws, size_t ws_size,
                              hipStream_t stream) {
  const float* x = (const float*)d_in[0];
  int* out = (int*)d_out;
  int B = in_sizes[0] / NPIX;
  k1_stream<<<8*B, 256, 0, stream>>>(x, out);
  k2_final <<<B,  1024, 0, stream>>>(out);
}

// Round 9
// 172.670 us; speedup vs baseline: 1.1629x; 1.0292x over previous
//
#include <hip/hip_runtime.h>
#include <stdint.h>

#define NPIX 65536
#define IGN (-255)
#define CAP 768          // LDS candidate list capacity per region (mean ~128, +32sigma)

// ---------------- threefry2x32 (exact JAX partitionable implementation) ----------------
__device__ __forceinline__ uint32_t rotl32(uint32_t v, uint32_t r){ return (v<<r)|(v>>(32u-r)); }

__device__ __forceinline__ void tf2x32(uint32_t k0, uint32_t k1, uint32_t x0, uint32_t x1,
                                       uint32_t &o0, uint32_t &o1){
  uint32_t k2 = k0 ^ k1 ^ 0x1BD11BDAu;
  x0 += k0; x1 += k1;
#define TFR(r) { x0 += x1; x1 = rotl32(x1,(r)); x1 ^= x0; }
  TFR(13u) TFR(15u) TFR(26u) TFR(6u)   x0 += k1; x1 += k2 + 1u;
  TFR(17u) TFR(29u) TFR(16u) TFR(24u)  x0 += k2; x1 += k0 + 2u;
  TFR(13u) TFR(15u) TFR(26u) TFR(6u)   x0 += k0; x1 += k1 + 3u;
  TFR(17u) TFR(29u) TFR(16u) TFR(24u)  x0 += k1; x1 += k2 + 4u;
  TFR(13u) TFR(15u) TFR(26u) TFR(6u)   x0 += k2; x1 += k0 + 5u;
#undef TFR
  o0 = x0; o1 = x1;
}

// two independent threefry chains, source-interleaved to force 2-way ILP.
// identical algebra to tf2x32 with x0=0, x1=x: a0=k0, a1=x+k1, then 20 rounds.
__device__ __forceinline__ void tf2_pair(uint32_t A0, uint32_t A1, uint32_t xA,
                                         uint32_t B0, uint32_t B1, uint32_t xB,
                                         uint32_t &rA, uint32_t &rB){
  uint32_t A2 = A0 ^ A1 ^ 0x1BD11BDAu;
  uint32_t B2 = B0 ^ B1 ^ 0x1BD11BDAu;
  uint32_t a0 = A0, a1 = xA + A1;
  uint32_t b0 = B0, b1 = xB + B1;
#define TFR2(r) { a0 += a1; b0 += b1; a1 = rotl32(a1,(r)); b1 = rotl32(b1,(r)); a1 ^= a0; b1 ^= b0; }
  TFR2(13u) TFR2(15u) TFR2(26u) TFR2(6u)
  a0 += A1; b0 += B1; a1 += A2 + 1u; b1 += B2 + 1u;
  TFR2(17u) TFR2(29u) TFR2(16u) TFR2(24u)
  a0 += A2; b0 += B2; a1 += A0 + 2u; b1 += B0 + 2u;
  TFR2(13u) TFR2(15u) TFR2(26u) TFR2(6u)
  a0 += A0; b0 += B0; a1 += A1 + 3u; b1 += B1 + 3u;
  TFR2(17u) TFR2(29u) TFR2(16u) TFR2(24u)
  a0 += A1; b0 += B1; a1 += A2 + 4u; b1 += B2 + 4u;
  TFR2(13u) TFR2(15u) TFR2(26u) TFR2(6u)
  a0 += A2; b0 += B2; a1 += A0 + 5u; b1 += B0 + 5u;
#undef TFR2
  rA = a0 ^ a1; rB = b0 ^ b1;
}

// pack score+index so that u64 max == (higher score, then lower index)
__device__ __forceinline__ unsigned long long packCand(uint32_t bits, uint32_t pix){
  float f = __uint_as_float((bits >> 9) | 0x3f800000u) - 1.0f;  // jax uniform [0,1)
  uint32_t u = __float_as_uint(f) ^ 0x80000000u;                // monotone map (f>=0)
  return ((unsigned long long)u << 32) | (unsigned long long)(0xFFFFFFFFu - pix);
}

// sorted-descending 10-element list, sentinel 0
__device__ __forceinline__ void t10_insert(unsigned long long* l, unsigned long long c){
  if (c > l[9]) {
    l[9] = c;
#pragma unroll
    for (int i = 9; i > 0; --i){
      unsigned long long a = l[i-1], b2 = l[i];
      if (b2 > a){ l[i-1] = b2; l[i] = a; }
    }
  }
}

// ---- single fused kernel ----
// pass1: read x, packed-u8 -> out[0..16383] (same-CU scratch), IGN-fill rest, hist
// then: shfl threshold -> paired-ILP scoring (u8 via L1/L2) -> wave-parallel top-10
// -> scratch IGN-fill -> dilated patches.  One dispatch total.
__global__ __launch_bounds__(1024)
void apm_kernel(const float* __restrict__ x, int* __restrict__ out){
  const int b = blockIdx.x;
  const int tid = threadIdx.x;
  const float* img = x + (size_t)b * NPIX;
  int* outb = out + (size_t)b * NPIX;

  __shared__ uint32_t histR[1024];          // 256 bins x 4 lane-columns (conflict spread)
  __shared__ float csum[256], cvsum[256];
  __shared__ uint32_t s_kw[4];
  __shared__ unsigned long long buf[2][CAP];
  __shared__ int s_cnt[2], s_fail[2], s_np[2];
  __shared__ int s_qthr, s_nroi;
  __shared__ unsigned long long s_top[2][64][10];
  __shared__ unsigned long long s_top2[2][8][10];
  __shared__ int s_pr[2][10], s_pc[2][10];

  histR[tid] = 0u;
  if (tid < 2){
    uint32_t o0, o1;
    tf2x32(0u, 1u, 0u, (uint32_t)(2*b + tid), o0, o1);
    s_kw[2*tid] = o0; s_kw[2*tid+1] = o1;
    s_cnt[tid] = 0;
  }
  __syncthreads();

  // ---- pass 1: read x (16 float4/thread = 64 px), u8->out scratch, IGN, histogram ----
  {
    const float4* x4 = (const float4*)img;
    int4* o4 = (int4*)outb;
    const int4 f4 = make_int4(IGN, IGN, IGN, IGN);
    const uint32_t c4 = (uint32_t)(tid & 3);
    for (int k = 0; k < 16; ++k){           // 16 x 1024 = 16384 float4 = 65536 px
      int i4 = tid + 1024*k;
      float4 v = x4[i4];
      uint32_t u0 = (uint32_t)min(max((int)floorf(v.x*255.0f),0),255);
      uint32_t u1 = (uint32_t)min(max((int)floorf(v.y*255.0f),0),255);
      uint32_t u2 = (uint32_t)min(max((int)floorf(v.z*255.0f),0),255);
      uint32_t u3 = (uint32_t)min(max((int)floorf(v.w*255.0f),0),255);
      outb[i4] = (int)(u0 | (u1<<8) | (u2<<16) | (u3<<24));  // packed word -> int i4
      if (i4 >= 4096) o4[i4] = f4;          // IGN ints 16384..65535 (skip u8 scratch)
      atomicAdd(&histR[(u0<<2)|c4],1u); atomicAdd(&histR[(u1<<2)|c4],1u);
      atomicAdd(&histR[(u2<<2)|c4],1u); atomicAdd(&histR[(u3<<2)|c4],1u);
    }
  }
  __syncthreads();

  // ---- threshold: wave 0 only, shuffle-based (verified R7 structure) ----
  // exactness: all partial sums are integers < 2^24 -> fp32 adds in any order
  // are bit-identical to jnp.cumsum.
  if (tid < 64){
    const int lane = tid;
    const int4* hv = (const int4*)&histR[16*lane];  // bins 4lane..4lane+3, 4 cols each
    int4 p0 = hv[0], p1 = hv[1], p2 = hv[2], p3 = hv[3];
    int h0 = p0.x + p0.y + p0.z + p0.w;
    int h1 = p1.x + p1.y + p1.z + p1.w;
    int h2 = p2.x + p2.y + p2.z + p2.w;
    int h3 = p3.x + p3.y + p3.z + p3.w;
    int cand = 256;
    if (h3) cand = 4*lane + 3;
    if (h2) cand = 4*lane + 2;
    if (h1) cand = 4*lane + 1;
    if (h0) cand = 4*lane + 0;
    for (int off = 32; off; off >>= 1) cand = min(cand, __shfl_xor(cand, off));
    const float img_min = (float)cand;
    float c0 = (float)h0, c1 = c0 + h1, c2 = c1 + h2, c3 = c2 + h3;
    float bv = 4.0f*lane - img_min;
    float v0 = h0*bv;
    float v1 = v0 + h1*(bv + 1.0f);
    float v2 = v1 + h2*(bv + 2.0f);
    float v3 = v2 + h3*(bv + 3.0f);
    float cc = c3, vv = v3;
    for (int off = 1; off < 64; off <<= 1){
      float a = __shfl_up(cc, off), b2 = __shfl_up(vv, off);
      if (lane >= off){ cc += a; vv += b2; }
    }
    const float cexc = cc - c3, vexc = vv - v3;
    const float cs0 = cexc+c0, cs1 = cexc+c1, cs2 = cexc+c2, cs3 = cexc+c3;
    const float vs0 = vexc+v0, vs1 = vexc+v1, vs2 = vexc+v2, vs3 = vexc+v3;
    csum[4*lane]   = cs0; csum[4*lane+1]  = cs1;
    csum[4*lane+2] = cs2; csum[4*lane+3]  = cs3;
    cvsum[4*lane]   = vs0; cvsum[4*lane+1] = vs1;
    cvsum[4*lane+2] = vs2; cvsum[4*lane+3] = vs3;
    const float ctot = __shfl(cc, 63), vtot = __shfl(vv, 63);
    const float s_tot_o = vtot + img_min * ctot;
    unsigned long long best = 0ull;
#define OTSU_BIN(CS, VS, J)                                              \
    { int bin = 4*lane + (J);                                            \
      if (bin < 255){                                                    \
        float w0_ = (CS);                                                \
        float w1_ = 65536.0f - w0_;                                      \
        float cs = (VS) + img_min * (CS);                                \
        float m0 = cs / fmaxf(w0_, 1e-12f);                              \
        float m1 = (s_tot_o - cs) / fmaxf(w1_, 1e-12f);                  \
        float d = m0 - m1;                                               \
        float vb = (w0_*w1_) * (d*d);                                    \
        unsigned long long pk =                                          \
          ((unsigned long long)__float_as_uint(vb) << 32) |              \
           (unsigned long long)(255 - bin);                              \
        if (pk > best) best = pk;                                        \
      } }
    OTSU_BIN(cs0, vs0, 0) OTSU_BIN(cs1, vs1, 1)
    OTSU_BIN(cs2, vs2, 2) OTSU_BIN(cs3, vs3, 3)
#undef OTSU_BIN
    for (int off = 32; off; off >>= 1){
      unsigned int hi = (unsigned int)(best >> 32), lo = (unsigned int)best;
      unsigned int hio = (unsigned int)__shfl_xor((int)hi, off);
      unsigned int loo = (unsigned int)__shfl_xor((int)lo, off);
      unsigned long long ob = ((unsigned long long)hio << 32) | loo;
      if (ob > best) best = ob;
    }
    if (lane == 0){
      int bestIdx = 255 - (int)(best & 0xFFFFFFFFull);
      float otsu = fminf(fmaxf((float)bestIdx, 1.0f), 254.0f);
      float n_tot = ctot, s_tot = vtot;
      float t_curr = otsu - img_min, t_prev = t_curr + 10.0f;
      int it = 0;
      while (fabsf(t_curr - t_prev) > 0.5f && it < 64){
        int idx = min(max((int)floorf(t_curr + img_min), 0), 255);
        float n_back = csum[idx], s_back = cvsum[idx];
        float n_fore = n_tot - n_back, s_fore = s_tot - s_back;
        float mean_back = (n_back > 0.0f) ? (s_back / fmaxf(n_back, 1.0f)) : 0.0f;
        float mean_fore = s_fore / fmaxf(n_fore, 1.0f);
        float t_next = (mean_back - mean_fore) /
                       (logf(fmaxf(mean_back, 1e-12f)) - logf(fmaxf(mean_fore, 1e-12f)));
        if (mean_back < 1e-12f) t_next = mean_fore * 0.5f;
        t_prev = t_curr; t_curr = t_next; ++it;
      }
      float lit = t_curr + img_min;
      // integer threshold: for integer q, (float)q > lit <=> q >= floor(lit)+1
      // NaN lit (degenerate image): predicate false for all q -> qthr=256
      int qthr;
      if (!(lit == lit)) qthr = 256;
      else               qthr = (int)floorf(lit) + 1;
      s_qthr = qthr;
      int nlo = (qthr <= 0) ? 0 : (int)csum[min(qthr, 256) - 1];
      s_nroi = NPIX - nlo;             // exact count(q > lit)
    }
  }
  __syncthreads();

  // ---- scoring: u8 from out scratch (L1/L2-local), paired threefry chains, LDS push ----
  const int qthr = s_qthr;
  const uint32_t fk0 = s_kw[0], fk1 = s_kw[1], bk0 = s_kw[2], bk1 = s_kw[3];
  const int4* u4 = (const int4*)outb;       // packed u8 as int4 (16 px each)
  for (int k = 0; k < 4; ++k){              // runtime loop: body ~8KB, I$-resident
    int4 w = u4[tid + 1024*k];
    uint32_t pw0 = (uint32_t)(16*(tid + 1024*k));
#pragma unroll
    for (int m = 0; m < 4; ++m){
      uint32_t pk = (m==0)?(uint32_t)w.x:(m==1)?(uint32_t)w.y:(m==2)?(uint32_t)w.z:(uint32_t)w.w;
      uint32_t pb = pw0 + (uint32_t)(4*m);
#pragma unroll
      for (int h = 0; h < 2; ++h){          // byte pairs (0,1) and (2,3)
        int qa = (int)((pk >> (16*h))     & 255u);
        int qb = (int)((pk >> (16*h + 8)) & 255u);
        bool ra = (qa >= qthr), rb = (qb >= qthr);
        uint32_t pixA = pb + (uint32_t)(2*h), pixB = pixA + 1u;
        uint32_t bitsA, bitsB;
        tf2_pair(ra ? fk0 : bk0, ra ? fk1 : bk1, pixA,
                 rb ? fk0 : bk0, rb ? fk1 : bk1, pixB, bitsA, bitsB);
        if (bitsA >= 0xFF000000u){          // top 1/256 slice, mantissa-aligned cut
          int r2 = ra ? 0 : 1;
          int idx = atomicAdd(&s_cnt[r2], 1);
          if (idx < CAP) buf[r2][idx] = packCand(bitsA, pixA);
        }
        if (bitsB >= 0xFF000000u){
          int r2 = rb ? 0 : 1;
          int idx = atomicAdd(&s_cnt[r2], 1);
          if (idx < CAP) buf[r2][idx] = packCand(bitsB, pixB);
        }
      }
    }
  }
  __syncthreads();

  // ---- validity: need (collected >= 10) or (collected == region size); no overflow ----
  if (tid < 2){
    int rs = tid ? (NPIX - s_nroi) : s_nroi;
    int cc = s_cnt[tid];
    s_fail[tid] = (cc > CAP) || (cc < 10 && cc != rs);
  }
  __syncthreads();

  // ---- per-lane top-10 (wave 0 -> fg, wave 1 -> bg); fallback rescans u8 scratch ----
  const int wv = tid >> 6, lane = tid & 63;
  if (wv < 2){
    const int r2 = wv;
    unsigned long long t[10];
#pragma unroll
    for (int i = 0; i < 10; ++i) t[i] = 0ull;
    if (!s_fail[r2]){
      int n = min(s_cnt[r2], CAP);
      for (int i = lane; i < n; i += 64) t10_insert(t, buf[r2][i]);
    } else {
      const uint32_t kk0 = s_kw[2*r2], kk1 = s_kw[2*r2+1];
      for (int k = 0; k < 1024; ++k){
        uint32_t pix = (uint32_t)(lane + 64*k);
        int q = (int)(((uint32_t)outb[pix >> 2] >> (8*(pix & 3u))) & 255u);
        bool r = (q >= qthr);
        if (r == (r2 == 0)){
          uint32_t o0, o1; tf2x32(kk0, kk1, 0u, pix, o0, o1);
          t10_insert(t, packCand(o0 ^ o1, pix));
        }
      }
    }
#pragma unroll
    for (int i = 0; i < 10; ++i) s_top[r2][lane][i] = t[i];
  }
  __syncthreads();
  // ---- merge 64 -> 8 ----
  if (wv < 2 && lane < 8){
    unsigned long long t[10];
#pragma unroll
    for (int i = 0; i < 10; ++i) t[i] = 0ull;
    for (int l2 = 0; l2 < 8; ++l2)
#pragma unroll
      for (int i = 0; i < 10; ++i) t10_insert(t, s_top[wv][lane*8 + l2][i]);
#pragma unroll
    for (int i = 0; i < 10; ++i) s_top2[wv][lane][i] = t[i];
  }
  __syncthreads();
  // ---- merge 8 -> 1, extract points ----
  if (wv < 2 && lane == 0){
    unsigned long long t[10];
#pragma unroll
    for (int i = 0; i < 10; ++i) t[i] = 0ull;
    for (int l2 = 0; l2 < 8; ++l2)
#pragma unroll
      for (int i = 0; i < 10; ++i) t10_insert(t, s_top2[wv][l2][i]);
    int np = 0;
    for (int i = 0; i < 10; ++i){
      if (t[i]){
        uint32_t pix = 0xFFFFFFFFu - (uint32_t)(t[i] & 0xFFFFFFFFull);
        s_pr[wv][np] = (int)(pix >> 8);
        s_pc[wv][np] = (int)(pix & 255u);
        ++np;
      }
    }
    s_np[wv] = np;
  }
  __syncthreads();

  // ---- overwrite u8 scratch ints 0..16383 with IGN (candidates already consumed) ----
  {
    int4* o4 = (int4*)outb;
    const int4 f4 = make_int4(IGN, IGN, IGN, IGN);
#pragma unroll
    for (int k = 0; k < 4; ++k) o4[tid + 1024*k] = f4;
  }
  __syncthreads();

  // ---- write dilated seed patches (<=180 px); duplicates write identical values ----
  const int nfg = s_np[0], nbg = s_np[1];
  const int npts = nfg + nbg;
  if (tid < npts*9){
    int k = tid / 9, d = tid - k*9;
    int pr = (k < nfg) ? s_pr[0][k] : s_pr[1][k - nfg];
    int pc = (k < nfg) ? s_pc[0][k] : s_pc[1][k - nfg];
    pr += d/3 - 1; pc += d%3 - 1;
    if (pr >= 0 && pr < 256 && pc >= 0 && pc < 256){
      bool fgd = false, bgd = false;
      for (int i = 0; i < nfg; ++i) fgd |= (abs(pr - s_pr[0][i]) <= 1) && (abs(pc - s_pc[0][i]) <= 1);
      for (int i = 0; i < nbg; ++i) bgd |= (abs(pr - s_pr[1][i]) <= 1) && (abs(pc - s_pc[1][i]) <= 1);
      int val = (fgd && bgd) ? IGN : (fgd ? 1 : 0);
      outb[pr*256 + pc] = val;
    }
  }
}

extern "C" void kernel_launch(void* const* d_in, const int* in_sizes, int n_in,
                              void* d_out, int out_size, void* d_ws, size_t ws_size,
                              hipStream_t stream) {
  const float* x = (const float*)d_in[0];
  int* out = (int*)d_out;
  int B = in_sizes[0] / NPIX;
  apm_kernel<<<B, 1024, 0, stream>>>(x, out);
}